// Round 1
// baseline (388.810 us; speedup 1.0000x reference)
//
#include <hip/hip_runtime.h>
#include <stdint.h>

#define N_NODES 100000
#define N_EDGES 800000
#define D 128

// ---------------- CSR build ----------------

__global__ void hist_kernel(const int* __restrict__ dst, int* __restrict__ cnt) {
    int e = blockIdx.x * blockDim.x + threadIdx.x;
    if (e < N_EDGES) atomicAdd(&cnt[dst[e]], 1);
}

// 1024 elements per block, 256 threads x 4 each. Writes local exclusive scan
// into offsets[i], block total into bs[blockIdx.x].
__global__ void scan_local(const int* __restrict__ cnt, int* __restrict__ offsets,
                           int* __restrict__ bs) {
    __shared__ int sdata[256];
    const int t = threadIdx.x;
    const int base = blockIdx.x * 1024 + t * 4;
    int v[4];
    int s = 0;
#pragma unroll
    for (int j = 0; j < 4; ++j) {
        int i = base + j;
        v[j] = (i < N_NODES) ? cnt[i] : 0;
        s += v[j];
    }
    sdata[t] = s;
    __syncthreads();
    int incl = s;
    for (int off = 1; off < 256; off <<= 1) {
        int add = (t >= off) ? sdata[t - off] : 0;
        __syncthreads();
        incl += add;
        sdata[t] = incl;
        __syncthreads();
    }
    int run = incl - s;  // exclusive prefix of this thread within block
#pragma unroll
    for (int j = 0; j < 4; ++j) {
        int i = base + j;
        if (i < N_NODES) offsets[i] = run;
        run += v[j];
    }
    if (t == 255) bs[blockIdx.x] = incl;  // block total
}

__global__ void scan_block(int* __restrict__ bs, int* __restrict__ offsets, int nblk) {
    if (threadIdx.x == 0) {
        int run = 0;
        for (int b = 0; b < nblk; ++b) {
            int t = bs[b];
            bs[b] = run;
            run += t;
        }
        offsets[N_NODES] = run;  // == N_EDGES
    }
}

__global__ void scan_add(int* __restrict__ offsets, const int* __restrict__ bs,
                         int* __restrict__ cursor) {
    const int t = threadIdx.x;
    const int base = blockIdx.x * 1024 + t * 4;
#pragma unroll
    for (int j = 0; j < 4; ++j) {
        int i = base + j;
        if (i < N_NODES) {
            int v = offsets[i] + bs[blockIdx.x];
            offsets[i] = v;
            cursor[i] = v;
        }
    }
}

__global__ void scatter_kernel(const int* __restrict__ src, const int* __restrict__ dst,
                               int* __restrict__ cursor, int* __restrict__ esrc) {
    int e = blockIdx.x * blockDim.x + threadIdx.x;
    if (e < N_EDGES) {
        int p = atomicAdd(&cursor[dst[e]], 1);
        esrc[p] = src[e];
    }
}

// ---------------- aggregation (mean of neighbor features) ----------------
// one block (128 threads) per node; thread d owns dim d; coalesced 512B row reads.
__global__ __launch_bounds__(128) void aggregate_kernel(const float* __restrict__ x,
                                                        const int* __restrict__ offsets,
                                                        const int* __restrict__ esrc,
                                                        float* __restrict__ hn) {
    const int n = blockIdx.x;
    const int d = threadIdx.x;
    const int s = offsets[n];
    const int e = offsets[n + 1];
    float acc = 0.f;
    for (int j = s; j < e; ++j) {
        int sn = esrc[j];
        acc += x[(long)sn * D + d];
    }
    float deg = (float)(e - s);
    hn[(long)n * D + d] = (e > s) ? acc / deg : 0.f;
}

// ---------------- fused GEMM: out = relu(x@Ws + hn@Wn + b) ----------------
// block: 256 threads, tile 64 rows x 128 cols (full width). fp32 vector FMA.
__global__ __launch_bounds__(256) void gemm_fused(const float* __restrict__ x,
                                                  const float* __restrict__ hn,
                                                  const float* __restrict__ Ws,
                                                  const float* __restrict__ Wn,
                                                  const float* __restrict__ bias,
                                                  float* __restrict__ out) {
    __shared__ float As[32][68];   // A tile transposed [k][row], stride 68 keeps 16B align
    __shared__ float Bs[32][128];
    const int tid = threadIdx.x;
    const int tx = tid & 31;   // col group (4 cols)
    const int ty = tid >> 5;   // row group (8 rows)
    const int row0 = blockIdx.x * 64;

    const int ar = tid >> 2;         // 0..63 : A row this thread stages
    const int ak = (tid & 3) * 8;    // 0,8,16,24 : k offset (8 consecutive k)
    const int brr = tid >> 3;        // 0..31 : B row this thread stages
    const int bc = (tid & 7) * 16;   // 16 consecutive cols

    float acc[8][4] = {};

    for (int m = 0; m < 2; ++m) {
        const float* A = m ? hn : x;
        const float* W = m ? Wn : Ws;
        for (int kt = 0; kt < 128; kt += 32) {
            const int grow = row0 + ar;
            float4 a0, a1;
            if (grow < N_NODES) {
                a0 = *(const float4*)&A[(long)grow * D + kt + ak];
                a1 = *(const float4*)&A[(long)grow * D + kt + ak + 4];
            } else {
                a0 = make_float4(0.f, 0.f, 0.f, 0.f);
                a1 = a0;
            }
            const float4* wsrc = (const float4*)&W[(long)(kt + brr) * D + bc];
            float4 b0 = wsrc[0], b1 = wsrc[1], b2 = wsrc[2], b3 = wsrc[3];
            __syncthreads();  // previous iter's LDS reads done
            As[ak + 0][ar] = a0.x; As[ak + 1][ar] = a0.y;
            As[ak + 2][ar] = a0.z; As[ak + 3][ar] = a0.w;
            As[ak + 4][ar] = a1.x; As[ak + 5][ar] = a1.y;
            As[ak + 6][ar] = a1.z; As[ak + 7][ar] = a1.w;
            float4* wdst = (float4*)&Bs[brr][bc];
            wdst[0] = b0; wdst[1] = b1; wdst[2] = b2; wdst[3] = b3;
            __syncthreads();
#pragma unroll
            for (int k = 0; k < 32; ++k) {
                float4 av0 = *(const float4*)&As[k][ty * 8];
                float4 av1 = *(const float4*)&As[k][ty * 8 + 4];
                float4 bv = *(const float4*)&Bs[k][tx * 4];
                float a[8] = {av0.x, av0.y, av0.z, av0.w, av1.x, av1.y, av1.z, av1.w};
                float bb[4] = {bv.x, bv.y, bv.z, bv.w};
#pragma unroll
                for (int r = 0; r < 8; ++r)
#pragma unroll
                    for (int c = 0; c < 4; ++c) acc[r][c] = fmaf(a[r], bb[c], acc[r][c]);
            }
        }
    }

    float4 bv = *(const float4*)&bias[tx * 4];
    float bb[4] = {bv.x, bv.y, bv.z, bv.w};
#pragma unroll
    for (int r = 0; r < 8; ++r) {
        int row = row0 + ty * 8 + r;
        if (row < N_NODES) {
            float4 o;
            o.x = fmaxf(acc[r][0] + bb[0], 0.f);
            o.y = fmaxf(acc[r][1] + bb[1], 0.f);
            o.z = fmaxf(acc[r][2] + bb[2], 0.f);
            o.w = fmaxf(acc[r][3] + bb[3], 0.f);
            *(float4*)&out[(long)row * D + tx * 4] = o;
        }
    }
}

// ---------------- launch ----------------

extern "C" void kernel_launch(void* const* d_in, const int* in_sizes, int n_in,
                              void* d_out, int out_size, void* d_ws, size_t ws_size,
                              hipStream_t stream) {
    const float* x  = (const float*)d_in[0];
    const int* src  = (const int*)d_in[1];
    const int* dst  = (const int*)d_in[2];
    const float* Ws = (const float*)d_in[3];
    const float* Wn = (const float*)d_in[4];
    const float* b  = (const float*)d_in[5];
    float* out = (float*)d_out;

    // workspace carve (all 4B types; hn aligned to 256B)
    int* cnt     = (int*)d_ws;                 // N
    int* offsets = cnt + N_NODES;              // N+1
    int* bs      = offsets + N_NODES + 1;      // 128
    int* cursor  = bs + 128;                   // N
    int* esrc    = cursor + N_NODES;           // E
    uintptr_t p = (uintptr_t)(esrc + N_EDGES);
    p = (p + 255) & ~(uintptr_t)255;
    float* hn = (float*)p;                     // N*D

    const int nblk_scan = (N_NODES + 1023) / 1024;  // 98

    hipMemsetAsync(cnt, 0, N_NODES * sizeof(int), stream);
    hist_kernel<<<(N_EDGES + 255) / 256, 256, 0, stream>>>(dst, cnt);
    scan_local<<<nblk_scan, 256, 0, stream>>>(cnt, offsets, bs);
    scan_block<<<1, 64, 0, stream>>>(bs, offsets, nblk_scan);
    scan_add<<<nblk_scan, 256, 0, stream>>>(offsets, bs, cursor);
    scatter_kernel<<<(N_EDGES + 255) / 256, 256, 0, stream>>>(src, dst, cursor, esrc);
    aggregate_kernel<<<N_NODES, 128, 0, stream>>>(x, offsets, esrc, hn);
    gemm_fused<<<(N_NODES + 63) / 64, 256, 0, stream>>>(x, hn, Ws, Wn, b, out);
}

// Round 3
// 335.398 us; speedup vs baseline: 1.1593x; 1.1593x over previous
//
#include <hip/hip_runtime.h>
#include <stdint.h>

#define N_NODES 100000
#define N_EDGES 800000
#define D 128

// ---------------- CSR build ----------------

// rank[e] = position of edge e within its dst bucket
__global__ void hist_rank(const int* __restrict__ dst, int* __restrict__ cnt,
                          int* __restrict__ rank) {
    int e = blockIdx.x * blockDim.x + threadIdx.x;
    if (e < N_EDGES) rank[e] = atomicAdd(&cnt[dst[e]], 1);
}

// 1024 elements per block, 256 threads x 4 each. Local exclusive scan into
// offsets[i], block total into bs[blockIdx.x].
__global__ void scan_local(const int* __restrict__ cnt, int* __restrict__ offsets,
                           int* __restrict__ bs) {
    __shared__ int sdata[256];
    const int t = threadIdx.x;
    const int base = blockIdx.x * 1024 + t * 4;
    int v[4];
    int s = 0;
#pragma unroll
    for (int j = 0; j < 4; ++j) {
        int i = base + j;
        v[j] = (i < N_NODES) ? cnt[i] : 0;
        s += v[j];
    }
    sdata[t] = s;
    __syncthreads();
    int incl = s;
    for (int off = 1; off < 256; off <<= 1) {
        int add = (t >= off) ? sdata[t - off] : 0;
        __syncthreads();
        incl += add;
        sdata[t] = incl;
        __syncthreads();
    }
    int run = incl - s;
#pragma unroll
    for (int j = 0; j < 4; ++j) {
        int i = base + j;
        if (i < N_NODES) offsets[i] = run;
        run += v[j];
    }
    if (t == 255) bs[blockIdx.x] = incl;
}

// one wave scans the (<=128) block sums
__global__ void scan_block2(int* __restrict__ bs, int* __restrict__ offsets, int nblk) {
    int t = threadIdx.x;  // 0..63
    int v0 = (2 * t < nblk) ? bs[2 * t] : 0;
    int v1 = (2 * t + 1 < nblk) ? bs[2 * t + 1] : 0;
    int s = v0 + v1;
    int incl = s;
    for (int off = 1; off < 64; off <<= 1) {
        int n = __shfl_up(incl, off, 64);
        if (t >= off) incl += n;
    }
    int excl = incl - s;
    if (2 * t < nblk) bs[2 * t] = excl;
    if (2 * t + 1 < nblk) bs[2 * t + 1] = excl + v0;
    if (t == 63) offsets[N_NODES] = incl;  // == N_EDGES
}

__global__ void scan_add(int* __restrict__ offsets, const int* __restrict__ bs) {
    const int t = threadIdx.x;
    const int base = blockIdx.x * 1024 + t * 4;
    const int add = bs[blockIdx.x];
#pragma unroll
    for (int j = 0; j < 4; ++j) {
        int i = base + j;
        if (i < N_NODES) offsets[i] += add;
    }
}

__global__ void scatter2(const int* __restrict__ src, const int* __restrict__ dst,
                         const int* __restrict__ offsets, const int* __restrict__ rank,
                         int* __restrict__ esrc) {
    int e = blockIdx.x * blockDim.x + threadIdx.x;
    if (e < N_EDGES) esrc[offsets[dst[e]] + rank[e]] = src[e];
}

// ---------------- aggregation: mean of neighbor rows ----------------
// one node per block; 8 edge-slots x 32 lanes (float4/lane) -> 8 gather rows
// in flight concurrently; LDS cross-slot reduction.
__global__ __launch_bounds__(256) void aggregate2(const float* __restrict__ x,
                                                  const int* __restrict__ offsets,
                                                  const int* __restrict__ esrc,
                                                  float* __restrict__ hn) {
    __shared__ float red[8][128];
    const int n = blockIdx.x;
    const int slot = threadIdx.x >> 5;     // 0..7
    const int c4 = (threadIdx.x & 31);     // float4 column group
    const int s = offsets[n];
    const int e = offsets[n + 1];
    float4 acc = make_float4(0.f, 0.f, 0.f, 0.f);
    for (int j = s + slot; j < e; j += 8) {
        int sn = esrc[j];
        float4 v = *(const float4*)&x[(long)sn * D + c4 * 4];
        acc.x += v.x; acc.y += v.y; acc.z += v.z; acc.w += v.w;
    }
    *(float4*)&red[slot][c4 * 4] = acc;
    __syncthreads();
    if (threadIdx.x < 128) {
        const int d = threadIdx.x;
        float ssum = 0.f;
#pragma unroll
        for (int r = 0; r < 8; ++r) ssum += red[r][d];
        int deg = e - s;
        hn[(long)n * D + d] = (deg > 0) ? ssum / (float)deg : 0.f;
    }
}

// ---------------- fused GEMM: out = relu(x@Ws + hn@Wn + b) ----------------
// 128x128 tile, 256 threads, 8x8 acc per thread, conflict-free LDS layout.
__global__ __launch_bounds__(256) void gemm_fused2(const float* __restrict__ x,
                                                   const float* __restrict__ hn,
                                                   const float* __restrict__ Ws,
                                                   const float* __restrict__ Wn,
                                                   const float* __restrict__ bias,
                                                   float* __restrict__ out) {
    __shared__ float As[32][128];  // [k][row]
    __shared__ float Bs[32][128];  // [k][col]
    const int tid = threadIdx.x;
    const int tx = tid & 15;   // col group: cols tx*4..+3 and tx*4+64..+67
    const int ty = tid >> 4;   // row group: rows ty*8..+7
    const int row0 = blockIdx.x * 128;

    const int ar = tid >> 1;          // A stage: row 0..127
    const int ac = (tid & 1) * 16;    // A stage: 16 consecutive k
    const int brr = tid >> 5;         // B stage: row 0..7 (+8 per pass)
    const int bc = (tid & 31) * 4;    // B stage: float4 col

    float acc[8][8] = {};

    for (int m = 0; m < 2; ++m) {
        const float* __restrict__ A = m ? hn : x;
        const float* __restrict__ W = m ? Wn : Ws;
        for (int kt = 0; kt < 128; kt += 32) {
            const long arow = row0 + ar;
            float4 a0, a1, a2, a3;
            if (arow < N_NODES) {
                const float4* ap = (const float4*)&A[arow * D + kt + ac];
                a0 = ap[0]; a1 = ap[1]; a2 = ap[2]; a3 = ap[3];
            } else {
                a0 = make_float4(0.f, 0.f, 0.f, 0.f);
                a1 = a0; a2 = a0; a3 = a0;
            }
            float4 b0 = *(const float4*)&W[(long)(kt + brr) * D + bc];
            float4 b1 = *(const float4*)&W[(long)(kt + brr + 8) * D + bc];
            float4 b2 = *(const float4*)&W[(long)(kt + brr + 16) * D + bc];
            float4 b3 = *(const float4*)&W[(long)(kt + brr + 24) * D + bc];
            __syncthreads();
            {
                float av[16] = {a0.x, a0.y, a0.z, a0.w, a1.x, a1.y, a1.z, a1.w,
                                a2.x, a2.y, a2.z, a2.w, a3.x, a3.y, a3.z, a3.w};
#pragma unroll
                for (int i = 0; i < 16; ++i) As[ac + i][ar] = av[i];
            }
            *(float4*)&Bs[brr][bc] = b0;
            *(float4*)&Bs[brr + 8][bc] = b1;
            *(float4*)&Bs[brr + 16][bc] = b2;
            *(float4*)&Bs[brr + 24][bc] = b3;
            __syncthreads();
#pragma unroll 4
            for (int k = 0; k < 32; ++k) {
                float4 av0 = *(const float4*)&As[k][ty * 8];
                float4 av1 = *(const float4*)&As[k][ty * 8 + 4];
                float4 bv0 = *(const float4*)&Bs[k][tx * 4];
                float4 bv1 = *(const float4*)&Bs[k][tx * 4 + 64];
                float a[8] = {av0.x, av0.y, av0.z, av0.w, av1.x, av1.y, av1.z, av1.w};
                float b[8] = {bv0.x, bv0.y, bv0.z, bv0.w, bv1.x, bv1.y, bv1.z, bv1.w};
#pragma unroll
                for (int r = 0; r < 8; ++r)
#pragma unroll
                    for (int c = 0; c < 8; ++c) acc[r][c] = fmaf(a[r], b[c], acc[r][c]);
            }
        }
    }

    float4 bb0 = *(const float4*)&bias[tx * 4];
    float4 bb1 = *(const float4*)&bias[tx * 4 + 64];
#pragma unroll
    for (int r = 0; r < 8; ++r) {
        int row = row0 + ty * 8 + r;
        if (row < N_NODES) {
            float4 o0, o1;
            o0.x = fmaxf(acc[r][0] + bb0.x, 0.f);
            o0.y = fmaxf(acc[r][1] + bb0.y, 0.f);
            o0.z = fmaxf(acc[r][2] + bb0.z, 0.f);
            o0.w = fmaxf(acc[r][3] + bb0.w, 0.f);
            o1.x = fmaxf(acc[r][4] + bb1.x, 0.f);
            o1.y = fmaxf(acc[r][5] + bb1.y, 0.f);
            o1.z = fmaxf(acc[r][6] + bb1.z, 0.f);
            o1.w = fmaxf(acc[r][7] + bb1.w, 0.f);
            *(float4*)&out[(long)row * D + tx * 4] = o0;
            *(float4*)&out[(long)row * D + tx * 4 + 64] = o1;
        }
    }
}

// ---------------- launch ----------------

extern "C" void kernel_launch(void* const* d_in, const int* in_sizes, int n_in,
                              void* d_out, int out_size, void* d_ws, size_t ws_size,
                              hipStream_t stream) {
    const float* x  = (const float*)d_in[0];
    const int* src  = (const int*)d_in[1];
    const int* dst  = (const int*)d_in[2];
    const float* Ws = (const float*)d_in[3];
    const float* Wn = (const float*)d_in[4];
    const float* b  = (const float*)d_in[5];
    float* out = (float*)d_out;

    // workspace carve
    int* cnt     = (int*)d_ws;                 // N
    int* offsets = cnt + N_NODES;              // N+1
    int* bs      = offsets + N_NODES + 1;      // 128
    int* rank    = bs + 128;                   // E
    int* esrc    = rank + N_EDGES;             // E
    uintptr_t p = (uintptr_t)(esrc + N_EDGES);
    p = (p + 255) & ~(uintptr_t)255;
    float* hn = (float*)p;                     // N*D

    const int nblk_scan = (N_NODES + 1023) / 1024;  // 98

    hipMemsetAsync(cnt, 0, N_NODES * sizeof(int), stream);
    hist_rank<<<(N_EDGES + 255) / 256, 256, 0, stream>>>(dst, cnt, rank);
    scan_local<<<nblk_scan, 256, 0, stream>>>(cnt, offsets, bs);
    scan_block2<<<1, 64, 0, stream>>>(bs, offsets, nblk_scan);
    scan_add<<<nblk_scan, 256, 0, stream>>>(offsets, bs);
    scatter2<<<(N_EDGES + 255) / 256, 256, 0, stream>>>(src, dst, offsets, rank, esrc);
    aggregate2<<<N_NODES, 256, 0, stream>>>(x, offsets, esrc, hn);
    gemm_fused2<<<(N_NODES + 127) / 128, 256, 0, stream>>>(x, hn, Ws, Wn, b, out);
}

// Round 4
// 321.542 us; speedup vs baseline: 1.2092x; 1.0431x over previous
//
#include <hip/hip_runtime.h>
#include <stdint.h>

#define N_NODES 100000
#define N_EDGES 800000
#define D 128

// ---------------- CSR build ----------------

__global__ void hist_rank(const int* __restrict__ dst, int* __restrict__ cnt,
                          int* __restrict__ rank) {
    int e = blockIdx.x * blockDim.x + threadIdx.x;
    if (e < N_EDGES) rank[e] = atomicAdd(&cnt[dst[e]], 1);
}

__global__ void scan_local(const int* __restrict__ cnt, int* __restrict__ offsets,
                           int* __restrict__ bs) {
    __shared__ int sdata[256];
    const int t = threadIdx.x;
    const int base = blockIdx.x * 1024 + t * 4;
    int v[4];
    int s = 0;
#pragma unroll
    for (int j = 0; j < 4; ++j) {
        int i = base + j;
        v[j] = (i < N_NODES) ? cnt[i] : 0;
        s += v[j];
    }
    sdata[t] = s;
    __syncthreads();
    int incl = s;
    for (int off = 1; off < 256; off <<= 1) {
        int add = (t >= off) ? sdata[t - off] : 0;
        __syncthreads();
        incl += add;
        sdata[t] = incl;
        __syncthreads();
    }
    int run = incl - s;
#pragma unroll
    for (int j = 0; j < 4; ++j) {
        int i = base + j;
        if (i < N_NODES) offsets[i] = run;
        run += v[j];
    }
    if (t == 255) bs[blockIdx.x] = incl;
}

__global__ void scan_block2(int* __restrict__ bs, int* __restrict__ offsets, int nblk) {
    int t = threadIdx.x;  // 0..63
    int v0 = (2 * t < nblk) ? bs[2 * t] : 0;
    int v1 = (2 * t + 1 < nblk) ? bs[2 * t + 1] : 0;
    int s = v0 + v1;
    int incl = s;
    for (int off = 1; off < 64; off <<= 1) {
        int n = __shfl_up(incl, off, 64);
        if (t >= off) incl += n;
    }
    int excl = incl - s;
    if (2 * t < nblk) bs[2 * t] = excl;
    if (2 * t + 1 < nblk) bs[2 * t + 1] = excl + v0;
    if (t == 63) offsets[N_NODES] = incl;
}

__global__ void scan_add(int* __restrict__ offsets, const int* __restrict__ bs) {
    const int t = threadIdx.x;
    const int base = blockIdx.x * 1024 + t * 4;
    const int add = bs[blockIdx.x];
#pragma unroll
    for (int j = 0; j < 4; ++j) {
        int i = base + j;
        if (i < N_NODES) offsets[i] += add;
    }
}

__global__ void scatter2(const int* __restrict__ src, const int* __restrict__ dst,
                         const int* __restrict__ offsets, const int* __restrict__ rank,
                         int* __restrict__ esrc) {
    int e = blockIdx.x * blockDim.x + threadIdx.x;
    if (e < N_EDGES) esrc[offsets[dst[e]] + rank[e]] = src[e];
}

// ---------------- dual-output GEMM ----------------
// pre = x@Ws + b  (written to out, no relu yet)
// y2  = x@Wn      (written to ws)
// tile: 128 rows x 64 cols, A staged once for both matmuls.
__global__ __launch_bounds__(256) void gemm_dual(const float* __restrict__ x,
                                                 const float* __restrict__ Ws,
                                                 const float* __restrict__ Wn,
                                                 const float* __restrict__ bias,
                                                 float* __restrict__ pre,
                                                 float* __restrict__ y2) {
    __shared__ float As[32][128];   // [k][row]
    __shared__ float Bss[32][68];   // [k][col] Ws tile (pad 68 = 16B-aligned rows)
    __shared__ float Bsn[32][68];   // [k][col] Wn tile
    const int tid = threadIdx.x;
    const int tx = tid & 15;    // col group: cols tx*4..+3
    const int ty = tid >> 4;    // row group: rows ty*8..+7
    const int row0 = (blockIdx.x >> 1) * 128;
    const int col0 = (blockIdx.x & 1) * 64;

    const int ar = tid >> 1;         // A stage row
    const int ac = (tid & 1) * 16;   // A stage k-offset (16 consecutive k)
    const int br = tid >> 4;         // B stage row 0..15 (and +16)
    const int bcg = (tid & 15) * 4;  // B stage float4 col

    float accs[8][4] = {};
    float accn[8][4] = {};

    for (int kt = 0; kt < 128; kt += 32) {
        const long arow = row0 + ar;
        float4 a0, a1, a2, a3;
        if (arow < N_NODES) {
            const float4* ap = (const float4*)&x[arow * D + kt + ac];
            a0 = ap[0]; a1 = ap[1]; a2 = ap[2]; a3 = ap[3];
        } else {
            a0 = make_float4(0.f, 0.f, 0.f, 0.f);
            a1 = a0; a2 = a0; a3 = a0;
        }
        float4 s0 = *(const float4*)&Ws[(long)(kt + br) * D + col0 + bcg];
        float4 s1 = *(const float4*)&Ws[(long)(kt + br + 16) * D + col0 + bcg];
        float4 n0 = *(const float4*)&Wn[(long)(kt + br) * D + col0 + bcg];
        float4 n1 = *(const float4*)&Wn[(long)(kt + br + 16) * D + col0 + bcg];
        __syncthreads();
        {
            float av[16] = {a0.x, a0.y, a0.z, a0.w, a1.x, a1.y, a1.z, a1.w,
                            a2.x, a2.y, a2.z, a2.w, a3.x, a3.y, a3.z, a3.w};
#pragma unroll
            for (int i = 0; i < 16; ++i) As[ac + i][ar] = av[i];
        }
        *(float4*)&Bss[br][bcg] = s0;
        *(float4*)&Bss[br + 16][bcg] = s1;
        *(float4*)&Bsn[br][bcg] = n0;
        *(float4*)&Bsn[br + 16][bcg] = n1;
        __syncthreads();
#pragma unroll 8
        for (int k = 0; k < 32; ++k) {
            float4 av0 = *(const float4*)&As[k][ty * 8];
            float4 av1 = *(const float4*)&As[k][ty * 8 + 4];
            float4 bsv = *(const float4*)&Bss[k][tx * 4];
            float4 bnv = *(const float4*)&Bsn[k][tx * 4];
            float a[8] = {av0.x, av0.y, av0.z, av0.w, av1.x, av1.y, av1.z, av1.w};
            float bs[4] = {bsv.x, bsv.y, bsv.z, bsv.w};
            float bn[4] = {bnv.x, bnv.y, bnv.z, bnv.w};
#pragma unroll
            for (int r = 0; r < 8; ++r) {
#pragma unroll
                for (int c = 0; c < 4; ++c) {
                    accs[r][c] = fmaf(a[r], bs[c], accs[r][c]);
                    accn[r][c] = fmaf(a[r], bn[c], accn[r][c]);
                }
            }
        }
    }

    float4 bb = *(const float4*)&bias[col0 + tx * 4];
#pragma unroll
    for (int r = 0; r < 8; ++r) {
        long row = row0 + ty * 8 + r;
        if (row < N_NODES) {
            float4 o, y;
            o.x = accs[r][0] + bb.x;
            o.y = accs[r][1] + bb.y;
            o.z = accs[r][2] + bb.z;
            o.w = accs[r][3] + bb.w;
            y.x = accn[r][0]; y.y = accn[r][1]; y.z = accn[r][2]; y.w = accn[r][3];
            *(float4*)&pre[row * D + col0 + tx * 4] = o;
            *(float4*)&y2[row * D + col0 + tx * 4] = y;
        }
    }
}

// ---------------- fused aggregate + epilogue ----------------
// out[n] = relu(pre[n] + mean_{e: dst=n} y2[src[e]])   (in-place on pre==out)
__global__ __launch_bounds__(256) void agg_ep(const float* __restrict__ y2,
                                              const int* __restrict__ offsets,
                                              const int* __restrict__ esrc,
                                              float* __restrict__ out) {
    __shared__ float red[8][128];
    const int n = blockIdx.x;
    const int slot = threadIdx.x >> 5;   // 0..7
    const int c4 = (threadIdx.x & 31);   // float4 col group
    const int s = offsets[n];
    const int e = offsets[n + 1];
    float4 acc = make_float4(0.f, 0.f, 0.f, 0.f);
    for (int j = s + slot; j < e; j += 8) {
        int sn = esrc[j];
        float4 v = *(const float4*)&y2[(long)sn * D + c4 * 4];
        acc.x += v.x; acc.y += v.y; acc.z += v.z; acc.w += v.w;
    }
    *(float4*)&red[slot][c4 * 4] = acc;
    __syncthreads();
    if (threadIdx.x < 128) {
        const int d = threadIdx.x;
        float ssum = 0.f;
#pragma unroll
        for (int r = 0; r < 8; ++r) ssum += red[r][d];
        int deg = e - s;
        float v = out[(long)n * D + d];
        if (deg > 0) v += ssum / (float)deg;
        out[(long)n * D + d] = fmaxf(v, 0.f);
    }
}

// ---------------- launch ----------------

extern "C" void kernel_launch(void* const* d_in, const int* in_sizes, int n_in,
                              void* d_out, int out_size, void* d_ws, size_t ws_size,
                              hipStream_t stream) {
    const float* x  = (const float*)d_in[0];
    const int* src  = (const int*)d_in[1];
    const int* dst  = (const int*)d_in[2];
    const float* Ws = (const float*)d_in[3];
    const float* Wn = (const float*)d_in[4];
    const float* b  = (const float*)d_in[5];
    float* out = (float*)d_out;

    int* cnt     = (int*)d_ws;                 // N
    int* offsets = cnt + N_NODES;              // N+1
    int* bs      = offsets + N_NODES + 1;      // 128
    int* rank    = bs + 128;                   // E
    int* esrc    = rank + N_EDGES;             // E
    uintptr_t p = (uintptr_t)(esrc + N_EDGES);
    p = (p + 255) & ~(uintptr_t)255;
    float* y2 = (float*)p;                     // N*D

    const int nblk_scan = (N_NODES + 1023) / 1024;  // 98

    hipMemsetAsync(cnt, 0, N_NODES * sizeof(int), stream);
    hist_rank<<<(N_EDGES + 255) / 256, 256, 0, stream>>>(dst, cnt, rank);
    scan_local<<<nblk_scan, 256, 0, stream>>>(cnt, offsets, bs);
    scan_block2<<<1, 64, 0, stream>>>(bs, offsets, nblk_scan);
    scan_add<<<nblk_scan, 256, 0, stream>>>(offsets, bs);
    scatter2<<<(N_EDGES + 255) / 256, 256, 0, stream>>>(src, dst, offsets, rank, esrc);
    gemm_dual<<<2 * ((N_NODES + 127) / 128), 256, 0, stream>>>(x, Ws, Wn, b, out, y2);
    agg_ep<<<N_NODES, 256, 0, stream>>>(y2, offsets, esrc, out);
}

// Round 5
// 302.672 us; speedup vs baseline: 1.2846x; 1.0623x over previous
//
#include <hip/hip_runtime.h>
#include <stdint.h>

#define N_NODES 100000
#define N_EDGES 800000
#define D 128

typedef _Float16 f16x8 __attribute__((ext_vector_type(8)));
typedef _Float16 f16x4 __attribute__((ext_vector_type(4)));
typedef float f32x4 __attribute__((ext_vector_type(4)));

// ---------------- CSR build ----------------

__global__ void hist_rank(const int* __restrict__ dst, int* __restrict__ cnt,
                          int* __restrict__ rank) {
    int e = blockIdx.x * blockDim.x + threadIdx.x;
    if (e < N_EDGES) rank[e] = atomicAdd(&cnt[dst[e]], 1);
}

__global__ void scan_local(const int* __restrict__ cnt, int* __restrict__ offsets,
                           int* __restrict__ bs) {
    __shared__ int sdata[256];
    const int t = threadIdx.x;
    const int base = blockIdx.x * 1024 + t * 4;
    int v[4];
    int s = 0;
#pragma unroll
    for (int j = 0; j < 4; ++j) {
        int i = base + j;
        v[j] = (i < N_NODES) ? cnt[i] : 0;
        s += v[j];
    }
    sdata[t] = s;
    __syncthreads();
    int incl = s;
    for (int off = 1; off < 256; off <<= 1) {
        int add = (t >= off) ? sdata[t - off] : 0;
        __syncthreads();
        incl += add;
        sdata[t] = incl;
        __syncthreads();
    }
    int run = incl - s;
#pragma unroll
    for (int j = 0; j < 4; ++j) {
        int i = base + j;
        if (i < N_NODES) offsets[i] = run;
        run += v[j];
    }
    if (t == 255) bs[blockIdx.x] = incl;
}

__global__ void scan_block2(int* __restrict__ bs, int* __restrict__ offsets, int nblk) {
    int t = threadIdx.x;  // 0..63
    int v0 = (2 * t < nblk) ? bs[2 * t] : 0;
    int v1 = (2 * t + 1 < nblk) ? bs[2 * t + 1] : 0;
    int s = v0 + v1;
    int incl = s;
    for (int off = 1; off < 64; off <<= 1) {
        int n = __shfl_up(incl, off, 64);
        if (t >= off) incl += n;
    }
    int excl = incl - s;
    if (2 * t < nblk) bs[2 * t] = excl;
    if (2 * t + 1 < nblk) bs[2 * t + 1] = excl + v0;
    if (t == 63) offsets[N_NODES] = incl;
}

__global__ void scan_add(int* __restrict__ offsets, const int* __restrict__ bs) {
    const int t = threadIdx.x;
    const int base = blockIdx.x * 1024 + t * 4;
    const int add = bs[blockIdx.x];
#pragma unroll
    for (int j = 0; j < 4; ++j) {
        int i = base + j;
        if (i < N_NODES) offsets[i] += add;
    }
}

__global__ void scatter2(const int* __restrict__ src, const int* __restrict__ dst,
                         const int* __restrict__ offsets, const int* __restrict__ rank,
                         int* __restrict__ esrc) {
    int e = blockIdx.x * blockDim.x + threadIdx.x;
    if (e < N_EDGES) esrc[offsets[dst[e]] + rank[e]] = src[e];
}

// ---------------- MFMA f16 GEMM ----------------
// blockIdx.x = 0: pre = x@Ws + b  -> out (fp32, no relu)
// blockIdx.x = 1: y2  = x@Wn      -> ws  (fp16)
// tile 128 rows x 128 cols, K=128 staged entirely (f16, XOR-swizzled LDS).
__device__ __forceinline__ uint32_t swz(uint32_t row, uint32_t kbyte) {
    return (row << 8) + (kbyte ^ ((row & 7u) << 4));
}

__global__ __launch_bounds__(256) void gemm_mfma(const float* __restrict__ x,
                                                 const float* __restrict__ Ws,
                                                 const float* __restrict__ Wn,
                                                 const float* __restrict__ bias,
                                                 float* __restrict__ pre,
                                                 _Float16* __restrict__ y2) {
    __shared__ char smem[65536];
    char* Ab = smem;            // 128 rows x 128 k f16, swizzled
    char* Bb = smem + 32768;    // 128 cols x 128 k f16 (transposed), swizzled

    const int tid = threadIdx.x;
    const int half = blockIdx.x;            // 0 = Ws/pre, 1 = Wn/y2
    const int row0 = blockIdx.y * 128;
    const float* __restrict__ W = half ? Wn : Ws;

    // ---- stage A: x[row0..row0+127][0..127] fp32 -> f16 swizzled ----
#pragma unroll
    for (int p = 0; p < 16; ++p) {
        int row = (tid >> 5) + p * 8;            // 0..127
        int c4 = (tid & 31) * 4;                 // k element (x4)
        long grow = row0 + row;
        float4 a = make_float4(0.f, 0.f, 0.f, 0.f);
        if (grow < N_NODES) a = *(const float4*)&x[grow * D + c4];
        f16x4 h;
        h[0] = (_Float16)a.x; h[1] = (_Float16)a.y;
        h[2] = (_Float16)a.z; h[3] = (_Float16)a.w;
        *(f16x4*)(Ab + swz(row, c4 * 2)) = h;
    }
    // ---- stage B: W[k][col] fp32 -> LDS[col][k] f16 swizzled ----
#pragma unroll
    for (int p = 0; p < 16; ++p) {
        int k = (tid >> 5) + p * 8;              // 0..127
        int cb = (tid & 31);                     // col base, stride 32
#pragma unroll
        for (int j = 0; j < 4; ++j) {
            int col = cb + 32 * j;
            float w = W[(long)k * D + col];
            *(_Float16*)(Bb + swz(col, k * 2)) = (_Float16)w;
        }
    }
    __syncthreads();

    const int lane = tid & 63;
    const int w = tid >> 6;        // wave 0..3
    const int wr = w >> 1;         // wave row 0..1 (64 rows)
    const int wc = w & 1;          // wave col 0..1 (64 cols)
    const int lrow = lane & 15;
    const int lkb = ((lane >> 4) * 8) * 2;  // kbase byte offset

    f32x4 acc[4][4];
#pragma unroll
    for (int i = 0; i < 4; ++i)
#pragma unroll
        for (int j = 0; j < 4; ++j) acc[i][j] = (f32x4){0.f, 0.f, 0.f, 0.f};

#pragma unroll
    for (int ks = 0; ks < 4; ++ks) {
        const int kb = ks * 64 + lkb;  // 32 halfs per ks = 64 bytes
        f16x8 af[4], bf[4];
#pragma unroll
        for (int fr = 0; fr < 4; ++fr)
            af[fr] = *(const f16x8*)(Ab + swz(wr * 64 + fr * 16 + lrow, kb));
#pragma unroll
        for (int fc = 0; fc < 4; ++fc)
            bf[fc] = *(const f16x8*)(Bb + swz(wc * 64 + fc * 16 + lrow, kb));
#pragma unroll
        for (int fr = 0; fr < 4; ++fr)
#pragma unroll
            for (int fc = 0; fc < 4; ++fc)
                acc[fr][fc] = __builtin_amdgcn_mfma_f32_16x16x32_f16(
                    af[fr], bf[fc], acc[fr][fc], 0, 0, 0);
    }

    // ---- epilogue: C[row][col], col = lane&15 + fc*16 + wc*64,
    //                row = (lane>>4)*4 + i + fr*16 + wr*64 ----
    const int rbase = row0 + wr * 64 + (lane >> 4) * 4;
    if (half == 0) {
#pragma unroll
        for (int fc = 0; fc < 4; ++fc) {
            const int colg = wc * 64 + fc * 16 + lrow;
            const float bv = bias[colg];
#pragma unroll
            for (int fr = 0; fr < 4; ++fr) {
#pragma unroll
                for (int i = 0; i < 4; ++i) {
                    long rowg = rbase + fr * 16 + i;
                    if (rowg < N_NODES) pre[rowg * D + colg] = acc[fr][fc][i] + bv;
                }
            }
        }
    } else {
#pragma unroll
        for (int fc = 0; fc < 4; ++fc) {
            const int colg = wc * 64 + fc * 16 + lrow;
#pragma unroll
            for (int fr = 0; fr < 4; ++fr) {
#pragma unroll
                for (int i = 0; i < 4; ++i) {
                    long rowg = rbase + fr * 16 + i;
                    if (rowg < N_NODES) y2[rowg * D + colg] = (_Float16)acc[fr][fc][i];
                }
            }
        }
    }
}

// ---------------- fused aggregate + epilogue ----------------
// out[n] = relu(pre[n] + mean_{e: dst=n} y2[src[e]])   (in-place, pre==out)
__global__ __launch_bounds__(256) void agg_ep(const _Float16* __restrict__ y2,
                                              const int* __restrict__ offsets,
                                              const int* __restrict__ esrc,
                                              float* __restrict__ out) {
    __shared__ float red[16][128];
    const int n = blockIdx.x;
    const int slot = threadIdx.x >> 4;   // 0..15
    const int c8 = threadIdx.x & 15;     // half8 col group (cols c8*8..+7)
    const int s = offsets[n];
    const int e = offsets[n + 1];
    float a[8] = {0.f, 0.f, 0.f, 0.f, 0.f, 0.f, 0.f, 0.f};
    for (int j = s + slot; j < e; j += 16) {
        int sn = esrc[j];
        f16x8 v = *(const f16x8*)&y2[(long)sn * D + c8 * 8];
#pragma unroll
        for (int i = 0; i < 8; ++i) a[i] += (float)v[i];
    }
    float4 lo = make_float4(a[0], a[1], a[2], a[3]);
    float4 hi = make_float4(a[4], a[5], a[6], a[7]);
    *(float4*)&red[slot][c8 * 8] = lo;
    *(float4*)&red[slot][c8 * 8 + 4] = hi;
    __syncthreads();
    if (threadIdx.x < 128) {
        const int d = threadIdx.x;
        float ssum = 0.f;
#pragma unroll
        for (int r = 0; r < 16; ++r) ssum += red[r][d];
        int deg = e - s;
        float v = out[(long)n * D + d];
        if (deg > 0) v += ssum / (float)deg;
        out[(long)n * D + d] = fmaxf(v, 0.f);
    }
}

// ---------------- launch ----------------

extern "C" void kernel_launch(void* const* d_in, const int* in_sizes, int n_in,
                              void* d_out, int out_size, void* d_ws, size_t ws_size,
                              hipStream_t stream) {
    const float* x  = (const float*)d_in[0];
    const int* src  = (const int*)d_in[1];
    const int* dst  = (const int*)d_in[2];
    const float* Ws = (const float*)d_in[3];
    const float* Wn = (const float*)d_in[4];
    const float* b  = (const float*)d_in[5];
    float* out = (float*)d_out;

    int* cnt     = (int*)d_ws;                 // N
    int* offsets = cnt + N_NODES;              // N+1
    int* bs      = offsets + N_NODES + 1;      // 128
    int* rank    = bs + 128;                   // E
    int* esrc    = rank + N_EDGES;             // E
    uintptr_t p = (uintptr_t)(esrc + N_EDGES);
    p = (p + 255) & ~(uintptr_t)255;
    _Float16* y2 = (_Float16*)p;               // N*D f16

    const int nblk_scan = (N_NODES + 1023) / 1024;  // 98

    hipMemsetAsync(cnt, 0, N_NODES * sizeof(int), stream);
    hist_rank<<<(N_EDGES + 255) / 256, 256, 0, stream>>>(dst, cnt, rank);
    scan_local<<<nblk_scan, 256, 0, stream>>>(cnt, offsets, bs);
    scan_block2<<<1, 64, 0, stream>>>(bs, offsets, nblk_scan);
    scan_add<<<nblk_scan, 256, 0, stream>>>(offsets, bs);
    scatter2<<<(N_EDGES + 255) / 256, 256, 0, stream>>>(src, dst, offsets, rank, esrc);
    dim3 ggrid(2, (N_NODES + 127) / 128);
    gemm_mfma<<<ggrid, 256, 0, stream>>>(x, Ws, Wn, b, out, y2);
    agg_ep<<<N_NODES, 256, 0, stream>>>(y2, offsets, esrc, out);
}